// Round 1
// baseline (417.420 us; speedup 1.0000x reference)
//
#include <hip/hip_runtime.h>

#define NH 16
#define HS 64
#define HID 1024
#define SEQ 2048
#define BB 4
#define MR (BB*SEQ)   // 8192 rows
#define KD 1024

typedef __bf16 bf16;
typedef __attribute__((ext_vector_type(8))) __bf16 bf16x8;
typedef __attribute__((ext_vector_type(4))) __bf16 bf16x4;
typedef __attribute__((ext_vector_type(4))) float f32x4;
typedef __attribute__((ext_vector_type(4))) float f4;

typedef __attribute__((address_space(3))) unsigned int as3u;
typedef __attribute__((address_space(1))) unsigned int as1u;

__device__ __forceinline__ void gl_lds16(const void* g, void* l) {
  __builtin_amdgcn_global_load_lds((const as1u*)g, (as3u*)l, 16, 0, 0);
}

__device__ __forceinline__ f32x4 mfma16(bf16x8 a, bf16x8 b, f32x4 c) {
  return __builtin_amdgcn_mfma_f32_16x16x32_bf16(a, b, c, 0, 0, 0);
}

// ---------------- fp32 -> bf16 conversion ----------------
__global__ __launch_bounds__(256) void k_cvt(const float* __restrict__ in,
                                             bf16* __restrict__ out, int n4) {
  int i = blockIdx.x * 256 + threadIdx.x;
  if (i >= n4) return;
  f4 v = reinterpret_cast<const f4*>(in)[i];
  bf16x4 h;
  h[0] = (bf16)v[0]; h[1] = (bf16)v[1]; h[2] = (bf16)v[2]; h[3] = (bf16)v[3];
  reinterpret_cast<bf16x4*>(out)[i] = h;
}

// ---------------- NT GEMM: C[m,n] = sum_k A[m,k]*W[n,k]  (both row-major along k) ----------------
// MODE 0: bf16 out, head-split layout [b][h][s][d], (acc+bias)*scale
// MODE 1: f32 out, flat [m][n], (acc+bias)*scale
template<int MODE>
__global__ __launch_bounds__(256) void k_gemm(const bf16* __restrict__ A,
                                              const bf16* __restrict__ Bw,
                                              const float* __restrict__ bias,
                                              void* __restrict__ outp, float scale) {
  __shared__ __align__(16) bf16 As[128*32];
  __shared__ __align__(16) bf16 Bs[128*32];
  const int tid = threadIdx.x;
  const int l = tid & 63, w = tid >> 6;
  const int m0 = blockIdx.x * 128, n0 = blockIdx.y * 128;
  const int wr = w >> 1, wc = w & 1;

  f32x4 acc[4][4] = {};

  // staging: chunk (w*2+j) covers LDS rows (w*2+j)*16..+15; lane l -> row +l/4, col (l&3)*8
  const int srow = 32*w + (l >> 2);
  const int scol = (l & 3) * 8;
  const bf16* Asrc = A  + (size_t)(m0 + srow) * KD + scol;
  const bf16* Bsrc = Bw + (size_t)(n0 + srow) * KD + scol;
  char* AsBase = (char*)As + (size_t)(w*2) * 1024;
  char* BsBase = (char*)Bs + (size_t)(w*2) * 1024;

  for (int kt = 0; kt < KD; kt += 32) {
    gl_lds16(Asrc + kt,                 AsBase);
    gl_lds16(Asrc + kt + (size_t)16*KD, AsBase + 1024);
    gl_lds16(Bsrc + kt,                 BsBase);
    gl_lds16(Bsrc + kt + (size_t)16*KD, BsBase + 1024);
    __syncthreads();   // drains vmcnt before reads

    bf16x8 af[4], bv[4];
    const int koff = (l >> 4) * 8;
    #pragma unroll
    for (int mf = 0; mf < 4; mf++)
      af[mf] = *reinterpret_cast<const bf16x8*>(&As[(wr*64 + mf*16 + (l & 15))*32 + koff]);
    #pragma unroll
    for (int nf = 0; nf < 4; nf++)
      bv[nf] = *reinterpret_cast<const bf16x8*>(&Bs[(wc*64 + nf*16 + (l & 15))*32 + koff]);
    #pragma unroll
    for (int mf = 0; mf < 4; mf++)
      #pragma unroll
      for (int nf = 0; nf < 4; nf++)
        acc[mf][nf] = mfma16(af[mf], bv[nf], acc[mf][nf]);
    __syncthreads();   // protect LDS reuse next iteration
  }

  #pragma unroll
  for (int mf = 0; mf < 4; mf++) {
    #pragma unroll
    for (int nf = 0; nf < 4; nf++) {
      const int n = n0 + wc*64 + nf*16 + (l & 15);
      const float bn = bias[n];
      #pragma unroll
      for (int j = 0; j < 4; j++) {
        const int m = m0 + wr*64 + mf*16 + (l >> 4)*4 + j;
        const float v = (acc[mf][nf][j] + bn) * scale;
        if (MODE == 0) {
          // head-split: [b][h][s][d]
          ((bf16*)outp)[(((size_t)(m >> 11) * NH + (n >> 6)) * SEQ + (m & (SEQ-1))) * HS + (n & 63)] = (bf16)v;
        } else {
          ((float*)outp)[(size_t)m * HID + n] = v;
        }
      }
    }
  }
}

// ---------------- causal flash attention ----------------
// Q,K,V: [B*NH][S][64] bf16, Q pre-scaled by 1/8. Out: [B*S][H] bf16 (merged heads).
__global__ __launch_bounds__(256) void k_attn(const bf16* __restrict__ Q,
                                              const bf16* __restrict__ K,
                                              const bf16* __restrict__ V,
                                              bf16* __restrict__ Aout) {
  const int qt = blockIdx.x;
  const int bh = blockIdx.y;
  const int q0 = qt * 64;
  const int tid = threadIdx.x, l = tid & 63, w = tid >> 6;

  __shared__ __align__(16) bf16 Qs[64*64];
  __shared__ __align__(16) bf16 Ks[64*64];
  __shared__ __align__(16) bf16 Vt[64*64];   // transposed: [d][kv]
  __shared__ __align__(16) bf16 Ps[64*64];

  const bf16* Qg = Q + (size_t)bh * SEQ * HS;
  const bf16* Kg = K + (size_t)bh * SEQ * HS;
  const bf16* Vg = V + (size_t)bh * SEQ * HS;

  // stage Q (swizzled rows of 128B: byte ^= (row&7)<<4 on 16B chunks)
  {
    const int r = tid >> 3;
    const int cb = (tid & 7) * 16;
    #pragma unroll
    for (int j = 0; j < 2; j++) {
      const int rr = r + j*32;
      bf16x8 v = *reinterpret_cast<const bf16x8*>(Qg + (size_t)(q0 + rr)*HS + cb/2);
      *reinterpret_cast<bf16x8*>((char*)Qs + rr*128 + (cb ^ ((rr & 7) << 4))) = v;
    }
  }
  __syncthreads();

  // hoist Q fragments (rows 16w..16w+15)
  bf16x8 qf[2];
  {
    const int row = 16*w + (l & 15);
    #pragma unroll
    for (int ks = 0; ks < 2; ks++) {
      const int cb = ks*64 + (l >> 4)*16;
      qf[ks] = *reinterpret_cast<const bf16x8*>((const char*)Qs + row*128 + (cb ^ ((row & 7) << 4)));
    }
  }

  float m_r[4], l_r[4];
  f32x4 o[4] = {};
  #pragma unroll
  for (int j = 0; j < 4; j++) { m_r[j] = -1e30f; l_r[j] = 0.f; }

  for (int kt = 0; kt <= qt; kt++) {
    const int k0 = kt * 64;
    __syncthreads();   // previous iteration's K/V reads done

    // stage K (swizzled) and V (transposed + swizzled)
    {
      const int r = tid >> 3;
      const int cb = (tid & 7) * 16;
      #pragma unroll
      for (int j = 0; j < 2; j++) {
        const int rr = r + j*32;
        bf16x8 kv = *reinterpret_cast<const bf16x8*>(Kg + (size_t)(k0 + rr)*HS + cb/2);
        *reinterpret_cast<bf16x8*>((char*)Ks + rr*128 + (cb ^ ((rr & 7) << 4))) = kv;
        bf16x8 vv = *reinterpret_cast<const bf16x8*>(Vg + (size_t)(k0 + rr)*HS + cb/2);
        #pragma unroll
        for (int i = 0; i < 8; i++) {
          const int d = cb/2 + i;
          *((bf16*)((char*)Vt + d*128 + ((rr*2) ^ ((d & 7) << 4)))) = vv[i];
        }
      }
    }
    __syncthreads();

    // S = Q K^T  (wave w: q rows 16w..+15, all 64 kv cols)
    f32x4 sc[4] = {};
    #pragma unroll
    for (int ks = 0; ks < 2; ks++) {
      const int cb = ks*64 + (l >> 4)*16;
      #pragma unroll
      for (int nf = 0; nf < 4; nf++) {
        const int row = nf*16 + (l & 15);
        bf16x8 kf = *reinterpret_cast<const bf16x8*>((const char*)Ks + row*128 + (cb ^ ((row & 7) << 4)));
        sc[nf] = mfma16(qf[ks], kf, sc[nf]);
      }
    }

    // causal mask on diagonal tile (q0 == k0 so local compare suffices)
    if (kt == qt) {
      const int qrow = 16*w + 4*(l >> 4);
      #pragma unroll
      for (int nf = 0; nf < 4; nf++) {
        const int kcol = nf*16 + (l & 15);
        #pragma unroll
        for (int j = 0; j < 4; j++)
          if (kcol > qrow + j) sc[nf][j] = -1e30f;
      }
    }

    // online softmax (rows live across 16 lanes; reduce over low-4 lane bits)
    float rmax[4];
    #pragma unroll
    for (int j = 0; j < 4; j++)
      rmax[j] = fmaxf(fmaxf(sc[0][j], sc[1][j]), fmaxf(sc[2][j], sc[3][j]));
    #pragma unroll
    for (int off = 1; off < 16; off <<= 1)
      #pragma unroll
      for (int j = 0; j < 4; j++)
        rmax[j] = fmaxf(rmax[j], __shfl_xor(rmax[j], off));

    float alpha[4];
    #pragma unroll
    for (int j = 0; j < 4; j++) {
      const float mn = fmaxf(m_r[j], rmax[j]);
      alpha[j] = __expf(m_r[j] - mn);
      m_r[j] = mn;
    }
    float rsum[4] = {0.f, 0.f, 0.f, 0.f};
    #pragma unroll
    for (int nf = 0; nf < 4; nf++)
      #pragma unroll
      for (int j = 0; j < 4; j++) {
        const float p = __expf(sc[nf][j] - m_r[j]);
        sc[nf][j] = p;
        rsum[j] += p;
      }
    #pragma unroll
    for (int off = 1; off < 16; off <<= 1)
      #pragma unroll
      for (int j = 0; j < 4; j++)
        rsum[j] += __shfl_xor(rsum[j], off);
    #pragma unroll
    for (int j = 0; j < 4; j++)
      l_r[j] = l_r[j] * alpha[j] + rsum[j];
    #pragma unroll
    for (int df = 0; df < 4; df++)
      #pragma unroll
      for (int j = 0; j < 4; j++)
        o[df][j] *= alpha[j];

    // write P (bf16, swizzled). Wave-local rows -> no barrier needed (lgkmcnt only).
    #pragma unroll
    for (int nf = 0; nf < 4; nf++)
      #pragma unroll
      for (int j = 0; j < 4; j++) {
        const int row = 16*w + 4*(l >> 4) + j;
        const int cbyte = (nf*16 + (l & 15)) * 2;
        *((bf16*)((char*)Ps + row*128 + (cbyte ^ ((row & 7) << 4)))) = (bf16)sc[nf][j];
      }

    // O += P V
    #pragma unroll
    for (int ks = 0; ks < 2; ks++) {
      const int prow = 16*w + (l & 15);
      const int pcb = ks*64 + (l >> 4)*16;
      bf16x8 pf = *reinterpret_cast<const bf16x8*>((const char*)Ps + prow*128 + (pcb ^ ((prow & 7) << 4)));
      #pragma unroll
      for (int df = 0; df < 4; df++) {
        const int vrow = df*16 + (l & 15);
        bf16x8 vf = *reinterpret_cast<const bf16x8*>((const char*)Vt + vrow*128 + (pcb ^ ((vrow & 7) << 4)));
        o[df] = mfma16(pf, vf, o[df]);
      }
    }
  }

  // epilogue: normalize, write merged-head bf16 [b*S+q][h*64+d]
  const int bb = bh >> 4, hh = bh & 15;
  #pragma unroll
  for (int j = 0; j < 4; j++) {
    const float inv = 1.0f / l_r[j];
    const int q = q0 + 16*w + 4*(l >> 4) + j;
    #pragma unroll
    for (int df = 0; df < 4; df++) {
      const int dcol = df*16 + (l & 15);
      Aout[(size_t)(bb * SEQ + q) * HID + hh*HS + dcol] = (bf16)(o[df][j] * inv);
    }
  }
}

// ---------------- launch ----------------
extern "C" void kernel_launch(void* const* d_in, const int* in_sizes, int n_in,
                              void* d_out, int out_size, void* d_ws, size_t ws_size,
                              hipStream_t stream) {
  const float* x  = (const float*)d_in[0];
  const float* Wq = (const float*)d_in[1];
  const float* bq = (const float*)d_in[2];
  const float* Wk = (const float*)d_in[3];
  const float* bk = (const float*)d_in[4];
  const float* Wv = (const float*)d_in[5];
  const float* bv = (const float*)d_in[6];
  const float* Wo = (const float*)d_in[7];
  const float* bo = (const float*)d_in[8];

  char* ws = (char*)d_ws;
  const size_t MB = 1024 * 1024;
  bf16* xb  = (bf16*)(ws);             // 16MB; reused as attn-out after V GEMM
  bf16* wqb = (bf16*)(ws + 16*MB);     // 2MB each
  bf16* wkb = (bf16*)(ws + 18*MB);
  bf16* wvb = (bf16*)(ws + 20*MB);
  bf16* wob = (bf16*)(ws + 22*MB);
  bf16* Qb  = (bf16*)(ws + 24*MB);     // 16MB each, [b][h][s][d]
  bf16* Kb  = (bf16*)(ws + 40*MB);
  bf16* Vb  = (bf16*)(ws + 56*MB);
  bf16* Ab  = xb;                      // alias: x-bf16 dead after V projection

  k_cvt<<<MR*HID/4/256, 256, 0, stream>>>(x,  xb,  MR*HID/4);
  k_cvt<<<HID*KD/4/256, 256, 0, stream>>>(Wq, wqb, HID*KD/4);
  k_cvt<<<HID*KD/4/256, 256, 0, stream>>>(Wk, wkb, HID*KD/4);
  k_cvt<<<HID*KD/4/256, 256, 0, stream>>>(Wv, wvb, HID*KD/4);
  k_cvt<<<HID*KD/4/256, 256, 0, stream>>>(Wo, wob, HID*KD/4);

  dim3 gg(MR/128, HID/128);
  k_gemm<0><<<gg, 256, 0, stream>>>(xb, wqb, bq, Qb, 0.125f);  // fold 1/sqrt(64) into Q
  k_gemm<0><<<gg, 256, 0, stream>>>(xb, wkb, bk, Kb, 1.0f);
  k_gemm<0><<<gg, 256, 0, stream>>>(xb, wvb, bv, Vb, 1.0f);

  k_attn<<<dim3(SEQ/64, BB*NH), 256, 0, stream>>>(Qb, Kb, Vb, Ab);

  k_gemm<1><<<gg, 256, 0, stream>>>(Ab, wob, bo, d_out, 1.0f);
}

// Round 2
// 225.240 us; speedup vs baseline: 1.8532x; 1.8532x over previous
//
#include <hip/hip_runtime.h>

#define NH 16
#define HS 64
#define HID 1024
#define SEQ 2048
#define BB 4
#define MR (BB*SEQ)   // 8192 rows
#define KD 1024

typedef __bf16 bf16;
typedef __attribute__((ext_vector_type(8))) __bf16 bf16x8;
typedef __attribute__((ext_vector_type(4))) __bf16 bf16x4;
typedef __attribute__((ext_vector_type(4))) float f32x4;
typedef __attribute__((ext_vector_type(4))) float f4;

typedef __attribute__((address_space(3))) unsigned int as3u;
typedef __attribute__((address_space(1))) unsigned int as1u;

__device__ __forceinline__ void gl_lds16(const void* g, void* l) {
  __builtin_amdgcn_global_load_lds((const as1u*)g, (as3u*)l, 16, 0, 0);
}

__device__ __forceinline__ f32x4 mfma16(bf16x8 a, bf16x8 b, f32x4 c) {
  return __builtin_amdgcn_mfma_f32_16x16x32_bf16(a, b, c, 0, 0, 0);
}

// ---------------- fp32 -> bf16 conversion ----------------
__global__ __launch_bounds__(256) void k_cvt(const float* __restrict__ in,
                                             bf16* __restrict__ out, int n4) {
  int i = blockIdx.x * 256 + threadIdx.x;
  if (i >= n4) return;
  f4 v = reinterpret_cast<const f4*>(in)[i];
  bf16x4 h;
  h[0] = (bf16)v[0]; h[1] = (bf16)v[1]; h[2] = (bf16)v[2]; h[3] = (bf16)v[3];
  reinterpret_cast<bf16x4*>(out)[i] = h;
}

// ---------------- NT GEMM: C[m,n] = sum_k A[m,k]*W[n,k] ----------------
// MODE 0: bf16 out, head-split [b][h][s][d], (acc+bias)*scale
// MODE 1: f32 out, flat [m][n]
// MODE 2: bf16 out, head-split TRANSPOSED [b][h][d][s]  (for V)
template<int MODE>
__global__ __launch_bounds__(256) void k_gemm(const bf16* __restrict__ A,
                                              const bf16* __restrict__ Bw,
                                              const float* __restrict__ bias,
                                              void* __restrict__ outp, float scale) {
  __shared__ __align__(16) bf16 As[128*32];
  __shared__ __align__(16) bf16 Bs[128*32];
  const int tid = threadIdx.x;
  const int l = tid & 63, w = tid >> 6;
  const int m0 = blockIdx.x * 128, n0 = blockIdx.y * 128;
  const int wr = w >> 1, wc = w & 1;

  f32x4 acc[4][4] = {};

  const int srow = 32*w + (l >> 2);
  const int scol = (l & 3) * 8;
  const bf16* Asrc = A  + (size_t)(m0 + srow) * KD + scol;
  const bf16* Bsrc = Bw + (size_t)(n0 + srow) * KD + scol;
  char* AsBase = (char*)As + (size_t)(w*2) * 1024;
  char* BsBase = (char*)Bs + (size_t)(w*2) * 1024;

  for (int kt = 0; kt < KD; kt += 32) {
    gl_lds16(Asrc + kt,                 AsBase);
    gl_lds16(Asrc + kt + (size_t)16*KD, AsBase + 1024);
    gl_lds16(Bsrc + kt,                 BsBase);
    gl_lds16(Bsrc + kt + (size_t)16*KD, BsBase + 1024);
    __syncthreads();

    bf16x8 af[4], bv[4];
    const int koff = (l >> 4) * 8;
    #pragma unroll
    for (int mf = 0; mf < 4; mf++)
      af[mf] = *reinterpret_cast<const bf16x8*>(&As[(wr*64 + mf*16 + (l & 15))*32 + koff]);
    #pragma unroll
    for (int nf = 0; nf < 4; nf++)
      bv[nf] = *reinterpret_cast<const bf16x8*>(&Bs[(wc*64 + nf*16 + (l & 15))*32 + koff]);
    #pragma unroll
    for (int mf = 0; mf < 4; mf++)
      #pragma unroll
      for (int nf = 0; nf < 4; nf++)
        acc[mf][nf] = mfma16(af[mf], bv[nf], acc[mf][nf]);
    __syncthreads();
  }

  #pragma unroll
  for (int mf = 0; mf < 4; mf++) {
    #pragma unroll
    for (int nf = 0; nf < 4; nf++) {
      const int n = n0 + wc*64 + nf*16 + (l & 15);
      const float bn = bias[n];
      #pragma unroll
      for (int j = 0; j < 4; j++) {
        const int m = m0 + wr*64 + mf*16 + (l >> 4)*4 + j;
        const float v = (acc[mf][nf][j] + bn) * scale;
        if (MODE == 0) {
          ((bf16*)outp)[(((size_t)(m >> 11) * NH + (n >> 6)) * SEQ + (m & (SEQ-1))) * HS + (n & 63)] = (bf16)v;
        } else if (MODE == 2) {
          ((bf16*)outp)[(((size_t)(m >> 11) * NH + (n >> 6)) * HS + (n & 63)) * SEQ + (m & (SEQ-1))] = (bf16)v;
        } else {
          ((float*)outp)[(size_t)m * HID + n] = v;
        }
      }
    }
  }
}

// ---------------- causal flash attention ----------------
// Q,K: [B*NH][S][64] bf16 (Q pre-scaled by 1/8). Vt: [B*NH][64][S] bf16 (transposed).
// Out: [B*S][HID] bf16 merged heads.
// Block: 8 waves, two Q-tiles of 128 rows (paired p and 15-p for balance).
__global__ __launch_bounds__(512) void k_attn(const bf16* __restrict__ Q,
                                              const bf16* __restrict__ K,
                                              const bf16* __restrict__ Vt,
                                              bf16* __restrict__ Aout) {
  const int bh = blockIdx.y;
  const int bx = blockIdx.x;
  const int tid = threadIdx.x, l = tid & 63, w = tid >> 6;

  __shared__ __align__(16) bf16 Qs[128*64];
  __shared__ __align__(16) bf16 Ks[2][64*64];
  __shared__ __align__(16) bf16 Vs[2][64*64];
  __shared__ __align__(16) bf16 Ps[128*64];

  const bf16* Qg = Q  + (size_t)bh * SEQ * HS;
  const bf16* Kg = K  + (size_t)bh * SEQ * HS;
  const bf16* Vg = Vt + (size_t)bh * HS * SEQ;   // [d][s]

  const int bb = bh >> 4, hh = bh & 15;
  const int sr  = tid >> 3;     // staging row 0..63
  const int sc8 = tid & 7;      // staging 16B-chunk 0..7
  const int swz = (sc8 ^ (sr & 7)) * 8;   // pre-swizzled source column (elements)

  for (int pass = 0; pass < 2; ++pass) {
    const int p  = pass ? (15 - bx) : bx;
    const int q0 = p * 128;
    const int nt = 2 * p + 2;

    __syncthreads();   // close previous pass's LDS reads

    // stage Q (128 rows) + KV tile 0, linear LDS dest, pre-swizzled source
    gl_lds16(Qg + (size_t)(q0 + sr)      * HS + swz, (char*)Qs        + w * 1024);
    gl_lds16(Qg + (size_t)(q0 + 64 + sr) * HS + swz, (char*)Qs + 8192 + w * 1024);
    gl_lds16(Kg + (size_t)sr * HS + swz,             (char*)Ks[0]     + w * 1024);
    gl_lds16(Vg + (size_t)sr * SEQ + swz,            (char*)Vs[0]     + w * 1024);
    __syncthreads();   // vmcnt drained: Q + kv0 ready

    // hoist Q fragments (wave w owns q rows 16w..16w+15 of the tile)
    bf16x8 qf[2];
    {
      const int row = 16 * w + (l & 15);
      #pragma unroll
      for (int ks = 0; ks < 2; ks++) {
        const int cc = ks * 4 + (l >> 4);
        qf[ks] = *reinterpret_cast<const bf16x8*>(
            (const char*)Qs + row * 128 + ((cc ^ (row & 7)) * 16));
      }
    }

    float m_r[4], l_r[4];
    f32x4 o[4] = {};
    #pragma unroll
    for (int j = 0; j < 4; j++) { m_r[j] = -1e30f; l_r[j] = 0.f; }

    int cur = 0;
    for (int kt = 0; kt < nt; ++kt) {
      const int k0 = kt * 64;

      // prefetch next tile early: latency hides under this tile's compute
      if (kt + 1 < nt) {
        const int k1 = k0 + 64;
        gl_lds16(Kg + (size_t)(k1 + sr) * HS + swz, (char*)Ks[cur ^ 1] + w * 1024);
        gl_lds16(Vg + (size_t)sr * SEQ + k1 + swz,  (char*)Vs[cur ^ 1] + w * 1024);
      }

      // wave skips tiles where all its q rows are masked
      if (k0 <= q0 + 16 * w + 15) {
        // S = Q K^T
        f32x4 scv[4] = {};
        #pragma unroll
        for (int ks = 0; ks < 2; ks++) {
          #pragma unroll
          for (int nf = 0; nf < 4; nf++) {
            const int kr = nf * 16 + (l & 15);
            const int cc = ks * 4 + (l >> 4);
            bf16x8 kf = *reinterpret_cast<const bf16x8*>(
                (const char*)Ks[cur] + kr * 128 + ((cc ^ (kr & 7)) * 16));
            scv[nf] = mfma16(qf[ks], kf, scv[nf]);
          }
        }

        // causal mask (only near-diagonal tiles need it)
        if (k0 + 63 > q0 + 16 * w) {
          const int qg_ = q0 + 16 * w + 4 * (l >> 4);
          #pragma unroll
          for (int nf = 0; nf < 4; nf++) {
            const int kg_ = k0 + nf * 16 + (l & 15);
            #pragma unroll
            for (int j = 0; j < 4; j++)
              if (kg_ > qg_ + j) scv[nf][j] = -1e30f;
          }
        }

        // online softmax (row over 16 lanes)
        float rmax[4];
        #pragma unroll
        for (int j = 0; j < 4; j++)
          rmax[j] = fmaxf(fmaxf(scv[0][j], scv[1][j]), fmaxf(scv[2][j], scv[3][j]));
        #pragma unroll
        for (int off = 1; off < 16; off <<= 1)
          #pragma unroll
          for (int j = 0; j < 4; j++)
            rmax[j] = fmaxf(rmax[j], __shfl_xor(rmax[j], off));

        float alpha[4];
        #pragma unroll
        for (int j = 0; j < 4; j++) {
          const float mn = fmaxf(m_r[j], rmax[j]);
          alpha[j] = __expf(m_r[j] - mn);
          m_r[j] = mn;
        }
        float rsum[4] = {0.f, 0.f, 0.f, 0.f};
        #pragma unroll
        for (int nf = 0; nf < 4; nf++)
          #pragma unroll
          for (int j = 0; j < 4; j++) {
            const float pp = __expf(scv[nf][j] - m_r[j]);
            scv[nf][j] = pp;
            rsum[j] += pp;
          }
        #pragma unroll
        for (int off = 1; off < 16; off <<= 1)
          #pragma unroll
          for (int j = 0; j < 4; j++)
            rsum[j] += __shfl_xor(rsum[j], off);
        #pragma unroll
        for (int j = 0; j < 4; j++)
          l_r[j] = l_r[j] * alpha[j] + rsum[j];
        #pragma unroll
        for (int df = 0; df < 4; df++)
          #pragma unroll
          for (int j = 0; j < 4; j++)
            o[df][j] *= alpha[j];

        // P -> LDS (bf16, swizzled); rows are wave-private
        #pragma unroll
        for (int nf = 0; nf < 4; nf++)
          #pragma unroll
          for (int j = 0; j < 4; j++) {
            const int row = 16 * w + 4 * (l >> 4) + j;
            const int cbyte = (nf * 16 + (l & 15)) * 2;
            *((bf16*)((char*)Ps + row * 128 + (cbyte ^ ((row & 7) << 4)))) = (bf16)scv[nf][j];
          }

        // O += P V  (Vs rows are d, cols kv)
        #pragma unroll
        for (int ks = 0; ks < 2; ks++) {
          const int prow = 16 * w + (l & 15);
          bf16x8 pf = *reinterpret_cast<const bf16x8*>(
              (const char*)Ps + prow * 128 + (((ks * 4 + (l >> 4)) * 16) ^ ((prow & 7) << 4)));
          #pragma unroll
          for (int df = 0; df < 4; df++) {
            const int vr = df * 16 + (l & 15);
            const int cc = ks * 4 + (l >> 4);
            bf16x8 vf = *reinterpret_cast<const bf16x8*>(
                (const char*)Vs[cur] + vr * 128 + ((cc ^ (vr & 7)) * 16));
            o[df] = mfma16(pf, vf, o[df]);
          }
        }
      }

      __syncthreads();   // publish prefetched buffer; close reads of current
      cur ^= 1;
    }

    // epilogue: normalize, write merged-head bf16 [b*S+q][h*64+d]
    #pragma unroll
    for (int j = 0; j < 4; j++) {
      const float inv = 1.0f / l_r[j];
      const int q = q0 + 16 * w + 4 * (l >> 4) + j;
      #pragma unroll
      for (int df = 0; df < 4; df++) {
        const int dcol = df * 16 + (l & 15);
        Aout[(size_t)(bb * SEQ + q) * HID + hh * HS + dcol] = (bf16)(o[df][j] * inv);
      }
    }
  }
}

// ---------------- launch ----------------
extern "C" void kernel_launch(void* const* d_in, const int* in_sizes, int n_in,
                              void* d_out, int out_size, void* d_ws, size_t ws_size,
                              hipStream_t stream) {
  const float* x  = (const float*)d_in[0];
  const float* Wq = (const float*)d_in[1];
  const float* bq = (const float*)d_in[2];
  const float* Wk = (const float*)d_in[3];
  const float* bk = (const float*)d_in[4];
  const float* Wv = (const float*)d_in[5];
  const float* bv = (const float*)d_in[6];
  const float* Wo = (const float*)d_in[7];
  const float* bo = (const float*)d_in[8];

  char* ws = (char*)d_ws;
  const size_t MB = 1024 * 1024;
  bf16* xb  = (bf16*)(ws);             // 16MB; reused as attn-out after V GEMM
  bf16* wqb = (bf16*)(ws + 16*MB);
  bf16* wkb = (bf16*)(ws + 18*MB);
  bf16* wvb = (bf16*)(ws + 20*MB);
  bf16* wob = (bf16*)(ws + 22*MB);
  bf16* Qb  = (bf16*)(ws + 24*MB);     // [b][h][s][d]
  bf16* Kb  = (bf16*)(ws + 40*MB);     // [b][h][s][d]
  bf16* Vb  = (bf16*)(ws + 56*MB);     // [b][h][d][s]  (transposed)
  bf16* Ab  = xb;

  k_cvt<<<MR*HID/4/256, 256, 0, stream>>>(x,  xb,  MR*HID/4);
  k_cvt<<<HID*KD/4/256, 256, 0, stream>>>(Wq, wqb, HID*KD/4);
  k_cvt<<<HID*KD/4/256, 256, 0, stream>>>(Wk, wkb, HID*KD/4);
  k_cvt<<<HID*KD/4/256, 256, 0, stream>>>(Wv, wvb, HID*KD/4);
  k_cvt<<<HID*KD/4/256, 256, 0, stream>>>(Wo, wob, HID*KD/4);

  dim3 gg(MR/128, HID/128);
  k_gemm<0><<<gg, 256, 0, stream>>>(xb, wqb, bq, Qb, 0.125f);
  k_gemm<0><<<gg, 256, 0, stream>>>(xb, wkb, bk, Kb, 1.0f);
  k_gemm<2><<<gg, 256, 0, stream>>>(xb, wvb, bv, Vb, 1.0f);

  k_attn<<<dim3(8, BB*NH), 512, 0, stream>>>(Qb, Kb, Vb, Ab);

  k_gemm<1><<<gg, 256, 0, stream>>>(Ab, wob, bo, d_out, 1.0f);
}